// Round 2
// baseline (29356.668 us; speedup 1.0000x reference)
//
#include <hip/hip_runtime.h>
#include <hip/hip_cooperative_groups.h>
#include <cmath>

namespace cg = cooperative_groups;

// Fixed problem shape (from reference): T=256, B=64, D=1024, H=1024
constexpr int TT = 256;
constexpr int BB = 64;
constexpr int DD = 1024;
constexpr int HH = 1024;
constexpr int KK = DD + HH;      // 2048
constexpr int NBLK = 256;        // one block per 4 hidden units
constexpr int NTHR = 256;
constexpr int HPB  = HH / NBLK;  // 4 h-units per block
constexpr int CK   = 64;         // k-chunk staged in LDS
constexpr int NP   = 8;          // k-partials per block
constexpr int ZPAD = 17;         // pad to break zred bank conflicts

__device__ __forceinline__ float sigm(float v) { return 1.0f / (1.0f + expf(-v)); }

// Block j computes, every step, the 64x16 pre-activation tile (4 gates x 4 h)
// for h in [4j,4j+4), then does the LSTM cell update for those cells locally.
// hx(t) lives in d_out[t] (it IS outputs[t]); cx lives in registers.
// One grid.sync() per step is the only inter-block dependency.
__global__ __launch_bounds__(NTHR, 1)
void qlstm_fused(const float* __restrict__ x,
                 const float* __restrict__ Wf, const float* __restrict__ bf, const float* __restrict__ gbf,
                 const float* __restrict__ Wi, const float* __restrict__ bi, const float* __restrict__ gbi,
                 const float* __restrict__ Wu, const float* __restrict__ bu, const float* __restrict__ gbu,
                 const float* __restrict__ Wo, const float* __restrict__ bo, const float* __restrict__ gbo,
                 float* __restrict__ out)
{
  cg::grid_group grid = cg::this_grid();

  __shared__ float comb[64 * CK];           // staged comb chunk, XOR-swizzled (16 KB)
  __shared__ float zred[NP * 64 * ZPAD];    // k-partial reduction buffer (34 KB)

  const int tid = threadIdx.x;
  const int h0  = blockIdx.x * HPB;

  // staging map: 64 rows x 4 segments of 16 floats
  const int srow = tid >> 2;        // 0..63
  const int sseg = tid & 3;         // 0..3
  const int sswz = (srow >> 2) & 7;
  // compute map: 16 row-groups x 2 col-groups x 8 k-parts
  const int cr  = tid & 15;         // rows cr*4..cr*4+3
  const int ccg = (tid >> 4) & 1;   // cols ccg*8..ccg*8+7 (of 16)
  const int cp  = tid >> 5;         // k quads {cp*2, cp*2+1} of each chunk
  // cell map: 64 batch rows x 4 h
  const int cb  = tid >> 2;
  const int chl = tid & 3;
  const int hcell = h0 + chl;

  const float* Wgate[4] = {Wf, Wi, Wu, Wo};

  // biases are t-invariant: hoist
  const float bfv = bf[hcell],  gbfv = gbf[hcell];
  const float biv = bi[hcell],  gbiv = gbi[hcell];
  const float buv = bu[hcell],  gbuv = gbu[hcell];
  const float bov = bo[hcell],  gbov = gbo[hcell];

  float cx = 0.0f, hxlast = 0.0f;

  float* __restrict__ hxout = out + (size_t)TT * BB * HH;
  float* __restrict__ cxout = hxout + (size_t)BB * HH;

  for (int t = 0; t < TT; ++t) {
    float acc[4][8];
    #pragma unroll
    for (int rr = 0; rr < 4; ++rr)
      #pragma unroll
      for (int cc = 0; cc < 8; ++cc) acc[rr][cc] = 0.0f;

    // t==0: hx is zero, skip the hx half of K entirely
    const int nchunk = (t == 0) ? (DD / CK) : (KK / CK);

    // prologue: register-prefetch chunk 0 (always from x)
    float4 v0, v1, v2, v3;
    {
      const float* src = x + (size_t)t * BB * DD + (size_t)srow * DD + sseg * 16;
      v0 = *(const float4*)(src + 0);
      v1 = *(const float4*)(src + 4);
      v2 = *(const float4*)(src + 8);
      v3 = *(const float4*)(src + 12);
    }

    for (int kc = 0; kc < nchunk; ++kc) {
      if (kc > 0) __syncthreads();      // previous compute done reading comb
      // write staged regs -> LDS; quad-XOR swizzle keeps writes AND reads
      // spread 8 lanes per 4-bank group (balanced for b128 ops)
      {
        const int kqb = sseg * 4;
        *(float4*)&comb[srow * CK + ((kqb + 0) ^ sswz) * 4] = v0;
        *(float4*)&comb[srow * CK + ((kqb + 1) ^ sswz) * 4] = v1;
        *(float4*)&comb[srow * CK + ((kqb + 2) ^ sswz) * 4] = v2;
        *(float4*)&comb[srow * CK + ((kqb + 3) ^ sswz) * 4] = v3;
      }
      __syncthreads();
      // issue next chunk's global loads now; latency hides under the FMAs below
      if (kc + 1 < nchunk) {
        const int kg = (kc + 1) * CK;
        const float* src;
        if (kg < DD) src = x   + (size_t)t       * BB * DD + kg;
        else         src = out + (size_t)(t - 1) * BB * HH + (kg - DD);
        src += (size_t)srow * 1024 + sseg * 16;   // x and out share row stride 1024
        v0 = *(const float4*)(src + 0);
        v1 = *(const float4*)(src + 4);
        v2 = *(const float4*)(src + 8);
        v3 = *(const float4*)(src + 12);
      }
      // compute chunk kc
      #pragma unroll
      for (int kq = 0; kq < 2; ++kq) {
        const int kqi = cp * 2 + kq;           // quad index within chunk
        const int kbase = kc * CK + kqi * 4;   // global k (== W's k index)
        float a[4][4];
        #pragma unroll
        for (int rr = 0; rr < 4; ++rr) {
          const int row = cr * 4 + rr;
          const float4 av = *(const float4*)&comb[row * CK + ((kqi ^ ((row >> 2) & 7)) * 4)];
          a[rr][0] = av.x; a[rr][1] = av.y; a[rr][2] = av.z; a[rr][3] = av.w;
        }
        #pragma unroll
        for (int cc = 0; cc < 8; ++cc) {
          const int col = ccg * 8 + cc;        // 0..15 = gate*4 + h_local
          const float* Wp = Wgate[col >> 2];
          const float4 wv = *(const float4*)&Wp[(size_t)(h0 + (col & 3)) * KK + kbase];
          #pragma unroll
          for (int rr = 0; rr < 4; ++rr) {
            acc[rr][cc] = fmaf(a[rr][0], wv.x, acc[rr][cc]);
            acc[rr][cc] = fmaf(a[rr][1], wv.y, acc[rr][cc]);
            acc[rr][cc] = fmaf(a[rr][2], wv.z, acc[rr][cc]);
            acc[rr][cc] = fmaf(a[rr][3], wv.w, acc[rr][cc]);
          }
        }
      }
    }

    // reduce the 8 k-partials through LDS
    __syncthreads();
    #pragma unroll
    for (int rr = 0; rr < 4; ++rr) {
      const int row = cr * 4 + rr;
      #pragma unroll
      for (int cc = 0; cc < 8; ++cc)
        zred[(cp * 64 + row) * ZPAD + ccg * 8 + cc] = acc[rr][cc];
    }
    __syncthreads();

    // LSTM cell update (one cell per thread)
    float zf = bfv, zi = biv, zu = buv, zo = bov;
    #pragma unroll
    for (int p = 0; p < NP; ++p) {
      const float* zr = &zred[(p * 64 + cb) * ZPAD];
      zf += zr[0  + chl];
      zi += zr[4  + chl];
      zu += zr[8  + chl];
      zo += zr[12 + chl];
    }
    const float fg = sigm(cosf(zf) + gbfv);   // QLinearGate: cos(z)+gb, then sigmoid
    const float ig = sigm(cosf(zi) + gbiv);
    const float gg = tanhf(cosf(zu) + gbuv);
    const float og = sigm(cosf(zo) + gbov);
    cx = fg * cx + ig * gg;
    const float hx = og * tanhf(cx);
    out[(size_t)t * BB * HH + (size_t)cb * HH + hcell] = hx;
    hxlast = hx;

    __threadfence();
    grid.sync();   // hx(t) visible to all blocks before step t+1
  }

  hxout[(size_t)cb * HH + hcell] = hxlast;
  cxout[(size_t)cb * HH + hcell] = cx;
}

extern "C" void kernel_launch(void* const* d_in, const int* in_sizes, int n_in,
                              void* d_out, int out_size, void* d_ws, size_t ws_size,
                              hipStream_t stream) {
  const float* x   = (const float*)d_in[0];
  const float* Wf  = (const float*)d_in[1];
  const float* bf_ = (const float*)d_in[2];
  const float* gbf = (const float*)d_in[3];
  const float* Wi  = (const float*)d_in[4];
  const float* bi_ = (const float*)d_in[5];
  const float* gbi = (const float*)d_in[6];
  const float* Wu  = (const float*)d_in[7];
  const float* bu_ = (const float*)d_in[8];
  const float* gbu = (const float*)d_in[9];
  const float* Wo  = (const float*)d_in[10];
  const float* bo_ = (const float*)d_in[11];
  const float* gbo = (const float*)d_in[12];
  float* out = (float*)d_out;

  void* args[] = {&x, &Wf, &bf_, &gbf, &Wi, &bi_, &gbi, &Wu, &bu_, &gbu,
                  &Wo, &bo_, &gbo, &out};
  hipLaunchCooperativeKernel((void*)qlstm_fused, dim3(NBLK), dim3(NTHR),
                             args, 0, stream);
}